// Round 9
// baseline (123.339 us; speedup 1.0000x reference)
//
#include <hip/hip_runtime.h>
#include <cstdint>
#include <cstddef>

// Poincare-ball (hyperbolic) attention block. B=2, S=2048, D=256, H=8, dh=32, c=1.
//
// Round 9:
//  - QKV + output projections moved to split-bf16 MFMA (C = xh*Wh + xh*Wl +
//    xl*Wh, fp32-grade accuracy, ~10x the fp32 VALU GEMM rate).
//  - attn K/table staging double-buffered: 1 barrier/tile, stage overlaps compute.
//  - combine4 emits AO as bf16 (h,l) pair; gemm_nn_small emits Wcomb as bf16 (h,l).

#define ALPHA 0.17677669529663687f   // 1/sqrt(32)
#define EMIN  -3.1129694f            // -ALPHA * log2((2-1e-5)/1e-5)  (clip)
#define CHI   1.95e-5f               // conservative 1-(1-1e-5)^2

typedef __bf16 bf16x8 __attribute__((ext_vector_type(8)));
typedef float  f32x4  __attribute__((ext_vector_type(4)));

__device__ __forceinline__ float fast_log2(float x) { return __builtin_amdgcn_logf(x); }
__device__ __forceinline__ float fast_exp2(float x) { return __builtin_amdgcn_exp2f(x); }

__device__ __forceinline__ void load_lds16(const void* g, void* l) {
  __builtin_amdgcn_global_load_lds((const __attribute__((address_space(1))) void*)g,
                                   (__attribute__((address_space(3))) void*)l, 16, 0, 0);
}

// ---------------------------------------------------------------------------
// Split fp32 -> bf16 (h) + bf16 (residual l). Covers x (1M floats) and
// Wq/Wk/Wv (3 x 64K floats). 8 floats/thread. Grid 608 x 256.
__global__ __launch_bounds__(256)
void split_all(const float* __restrict__ x, const float* __restrict__ Wq,
               const float* __restrict__ Wk, const float* __restrict__ Wv,
               __bf16* __restrict__ xh, __bf16* __restrict__ xl,
               __bf16* __restrict__ Ws) {
  int g = blockIdx.x * 256 + threadIdx.x;
  const float* src;
  __bf16 *dh, *dl;
  if (g < 131072) {                       // x: 1,048,576 floats
    src = x + (size_t)g * 8; dh = xh + (size_t)g * 8; dl = xl + (size_t)g * 8;
  } else {
    int e = g - 131072;                   // 0..24575
    int wsel = e >> 13;                   // 8192 threads per W
    int inner = (e & 8191) * 8;
    src = (wsel == 0 ? Wq : (wsel == 1 ? Wk : Wv)) + inner;
    dh = Ws + wsel * 131072 + inner;
    dl = Ws + wsel * 131072 + 65536 + inner;
  }
  union { __bf16 h[8]; uint4 u; } ph, pl;
#pragma unroll
  for (int i = 0; i < 2; ++i) {
    float4 v = *(const float4*)(src + i * 4);
    float vv[4] = {v.x, v.y, v.z, v.w};
#pragma unroll
    for (int j = 0; j < 4; ++j) {
      __bf16 hb = (__bf16)vv[j];
      ph.h[i * 4 + j] = hb;
      pl.h[i * 4 + j] = (__bf16)(vv[j] - (float)hb);
    }
  }
  *(uint4*)dh = ph.u;
  *(uint4*)dl = pl.u;
}

// ---------------------------------------------------------------------------
// Fused QKV projection, split-bf16 MFMA. Grid (64, 12), 4 waves.
// nb>>2 selects {Q,K,V}; block covers rows m0..m0+63, cols (nb&3)*64..+63.
// Wave w owns rows m0+w*16..+15 x all 64 cols. Head-major fp32 output.
__global__ __launch_bounds__(256)
void gemm_qkv_mfma(const __bf16* __restrict__ xh, const __bf16* __restrict__ xl,
                   const __bf16* __restrict__ Ws,
                   const float* __restrict__ bq, const float* __restrict__ bk,
                   const float* __restrict__ bv,
                   float* __restrict__ Qb, float* __restrict__ Kb,
                   float* __restrict__ Vb) {
  const int tid = threadIdx.x, w = tid >> 6, lane = tid & 63;
  const int l15 = lane & 15, lg = lane >> 4;
  const int m0 = blockIdx.x * 64, nb = blockIdx.y;
  const int wsel = nb >> 2;
  const int n256b = (nb & 3) * 64;
  const __bf16* Wh = Ws + wsel * 131072;
  const __bf16* Wl = Wh + 65536;
  const int arow = m0 + w * 16 + l15;
  const __bf16* axh = xh + (size_t)arow * 256 + lg * 8;
  const __bf16* axl = xl + (size_t)arow * 256 + lg * 8;
  f32x4 acc0 = {0,0,0,0}, acc1 = {0,0,0,0}, acc2 = {0,0,0,0}, acc3 = {0,0,0,0};
#pragma unroll
  for (int k0 = 0; k0 < 256; k0 += 32) {
    bf16x8 ah = *(const bf16x8*)(axh + k0);
    bf16x8 al = *(const bf16x8*)(axl + k0);
#pragma unroll
    for (int g = 0; g < 4; ++g) {
      const size_t br = (size_t)(n256b + g * 16 + l15) * 256 + lg * 8 + k0;
      bf16x8 bh = *(const bf16x8*)(Wh + br);
      bf16x8 bl = *(const bf16x8*)(Wl + br);
      f32x4& acc = g == 0 ? acc0 : (g == 1 ? acc1 : (g == 2 ? acc2 : acc3));
      acc = __builtin_amdgcn_mfma_f32_16x16x32_bf16(ah, bh, acc, 0, 0, 0);
      acc = __builtin_amdgcn_mfma_f32_16x16x32_bf16(al, bh, acc, 0, 0, 0);
      acc = __builtin_amdgcn_mfma_f32_16x16x32_bf16(ah, bl, acc, 0, 0, 0);
    }
  }
  const float* bias = wsel == 0 ? bq : (wsel == 1 ? bk : bv);
  float* C = wsel == 0 ? Qb : (wsel == 1 ? Kb : Vb);
#pragma unroll
  for (int g = 0; g < 4; ++g) {
    const f32x4& acc = g == 0 ? acc0 : (g == 1 ? acc1 : (g == 2 ? acc2 : acc3));
    int n256 = n256b + g * 16 + l15;
    float bval = bias[n256];
    int h = n256 >> 5, d = n256 & 31;
#pragma unroll
    for (int r = 0; r < 4; ++r) {
      int m = m0 + w * 16 + lg * 4 + r;
      int b = m >> 11, s = m & 2047;
      C[((size_t)((b << 3) + h) << 16) + (size_t)s * 32 + d] = acc[r] + bval;
    }
  }
}

// ---------------------------------------------------------------------------
// Output projection, split-bf16 MFMA: out = AO @ Wcomb^T + bcomb. Grid (64,4).
__global__ __launch_bounds__(256)
void gemm_out_mfma(const __bf16* __restrict__ aoh, const __bf16* __restrict__ aol,
                   const __bf16* __restrict__ Wch, const __bf16* __restrict__ Wcl,
                   const float* __restrict__ bcomb, float* __restrict__ out) {
  const int tid = threadIdx.x, w = tid >> 6, lane = tid & 63;
  const int l15 = lane & 15, lg = lane >> 4;
  const int m0 = blockIdx.x * 64, n0 = blockIdx.y * 64;
  const int arow = m0 + w * 16 + l15;
  const __bf16* axh = aoh + (size_t)arow * 256 + lg * 8;
  const __bf16* axl = aol + (size_t)arow * 256 + lg * 8;
  f32x4 acc0 = {0,0,0,0}, acc1 = {0,0,0,0}, acc2 = {0,0,0,0}, acc3 = {0,0,0,0};
#pragma unroll
  for (int k0 = 0; k0 < 256; k0 += 32) {
    bf16x8 ah = *(const bf16x8*)(axh + k0);
    bf16x8 al = *(const bf16x8*)(axl + k0);
#pragma unroll
    for (int g = 0; g < 4; ++g) {
      const size_t br = (size_t)(n0 + g * 16 + l15) * 256 + lg * 8 + k0;
      bf16x8 bh = *(const bf16x8*)(Wch + br);
      bf16x8 bl = *(const bf16x8*)(Wcl + br);
      f32x4& acc = g == 0 ? acc0 : (g == 1 ? acc1 : (g == 2 ? acc2 : acc3));
      acc = __builtin_amdgcn_mfma_f32_16x16x32_bf16(ah, bh, acc, 0, 0, 0);
      acc = __builtin_amdgcn_mfma_f32_16x16x32_bf16(al, bh, acc, 0, 0, 0);
      acc = __builtin_amdgcn_mfma_f32_16x16x32_bf16(ah, bl, acc, 0, 0, 0);
    }
  }
#pragma unroll
  for (int g = 0; g < 4; ++g) {
    const f32x4& acc = g == 0 ? acc0 : (g == 1 ? acc1 : (g == 2 ? acc2 : acc3));
    int n = n0 + g * 16 + l15;
    float bval = bcomb[n];
#pragma unroll
    for (int r = 0; r < 4; ++r) {
      int m = m0 + w * 16 + lg * 4 + r;
      out[(size_t)m * 256 + n] = acc[r] + bval;
    }
  }
}

// ---------------------------------------------------------------------------
// Wcomb = Wfc @ Wo (NN, 256^3), fp32 compute, bf16 h/l output. Grid (4,4).
__global__ __launch_bounds__(256)
void gemm_nn_small(const float* __restrict__ Afc, const float* __restrict__ Bo,
                   __bf16* __restrict__ Ch, __bf16* __restrict__ Cl) {
  __shared__ float AsT[32][68];
  __shared__ float Bs[32][68];
  const int tid = threadIdx.x;
  const int ty = tid >> 4, tx = tid & 15;
  const int m0 = blockIdx.x * 64;
  const int n0 = blockIdx.y * 64;
  float acc[4][4] = {};
  for (int k0 = 0; k0 < 256; k0 += 32) {
#pragma unroll
    for (int jj = 0; jj < 2; ++jj) {
      int j = tid * 2 + jj;
      {
        int r = j >> 3, c4 = (j & 7) << 2;
        float4 av = *(const float4*)&Afc[(size_t)(m0 + r) * 256 + k0 + c4];
        AsT[c4 + 0][r] = av.x; AsT[c4 + 1][r] = av.y;
        AsT[c4 + 2][r] = av.z; AsT[c4 + 3][r] = av.w;
      }
      {
        int r = j >> 4, c4 = (j & 15) << 2;
        *(float4*)&Bs[r][c4] = *(const float4*)&Bo[(size_t)(k0 + r) * 256 + n0 + c4];
      }
    }
    __syncthreads();
#pragma unroll
    for (int kk = 0; kk < 32; ++kk) {
      float4 a = *(const float4*)&AsT[kk][ty * 4];
      float4 b = *(const float4*)&Bs[kk][tx * 4];
      float av[4] = {a.x, a.y, a.z, a.w};
      float bv[4] = {b.x, b.y, b.z, b.w};
#pragma unroll
      for (int i = 0; i < 4; ++i)
#pragma unroll
        for (int j2 = 0; j2 < 4; ++j2)
          acc[i][j2] = fmaf(av[i], bv[j2], acc[i][j2]);
    }
    __syncthreads();
  }
#pragma unroll
  for (int i = 0; i < 4; ++i) {
    union { __bf16 h[4]; uint2 u; } ph, pl;
#pragma unroll
    for (int j = 0; j < 4; ++j) {
      __bf16 hb = (__bf16)acc[i][j];
      ph.h[j] = hb;
      pl.h[j] = (__bf16)(acc[i][j] - (float)hb);
    }
    size_t off = (size_t)(m0 + ty * 4 + i) * 256 + n0 + tx * 4;
    *(uint2*)(Ch + off) = ph.u;
    *(uint2*)(Cl + off) = pl.u;
  }
}

// ---------------------------------------------------------------------------
// bcomb = Wfc @ bo + bfc. Grid 16 blocks x 16 rows.
__global__ __launch_bounds__(256)
void bcomb_k(const float* __restrict__ Wfc, const float* __restrict__ bo,
             const float* __restrict__ bfc, float* __restrict__ bcomb) {
  __shared__ float red[256];
  int r = threadIdx.x >> 4, c = threadIdx.x & 15;
  int row = blockIdx.x * 16 + r;
  float s = 0.0f;
  for (int k = c; k < 256; k += 16) s = fmaf(Wfc[(size_t)row * 256 + k], bo[k], s);
  red[threadIdx.x] = s;
  __syncthreads();
  if (c == 0) {
    float t = 0.0f;
#pragma unroll
    for (int i = 0; i < 16; ++i) t += red[r * 16 + i];
    bcomb[row] = t + bfc[row];
  }
}

// ---------------------------------------------------------------------------
// expmap0 -> bf16 rows + tables.
// Q rows -> qtab4 = (qq, ALPHA*log2 B, B, 0).  K rows -> ktab4 = (kk, B, ALPHA*log2 B, 0).
__global__ __launch_bounds__(256)
void prep_qk(const float* __restrict__ Qf, const float* __restrict__ Kf,
             __bf16* __restrict__ Qbf, __bf16* __restrict__ Kbf,
             float4* __restrict__ qtab4, float4* __restrict__ ktab4) {
  int idx = blockIdx.x * 256 + threadIdx.x;   // 0..65535
  const bool isQ = idx < 32768;
  const int i2 = isQ ? idx : idx - 32768;
  const float* src = (isQ ? Qf : Kf) + (size_t)i2 * 32;
  __bf16* dst = (isQ ? Qbf : Kbf) + (size_t)i2 * 32;
  float v[32];
  float ss = 0.0f;
#pragma unroll
  for (int i = 0; i < 8; ++i) {
    float4 v4 = *(const float4*)&src[i * 4];
    v[i*4+0] = v4.x; v[i*4+1] = v4.y; v[i*4+2] = v4.z; v[i*4+3] = v4.w;
    ss = fmaf(v4.x, v4.x, ss); ss = fmaf(v4.y, v4.y, ss);
    ss = fmaf(v4.z, v4.z, ss); ss = fmaf(v4.w, v4.w, ss);
  }
  ss = fmaxf(ss, 1e-12f);
  float x  = sqrtf(ss);
  float ex = fast_exp2(-2.8853900817779268f * x);       // e^{-2x}
  float opex = 1.0f + ex;
  float th = (1.0f - ex) / opex;
  float sc = th / x;
  float qq = th * th;
  float Bv = 4.0f * ex / (opex * opex);                  // 1 - qq, exact
  float lgB = 2.0f - 2.8853900817779268f * x - 2.0f * fast_log2(opex);
  if (isQ) qtab4[i2] = float4{qq, ALPHA * lgB, Bv, 0.0f};
  else     ktab4[i2] = float4{qq, Bv, ALPHA * lgB, 0.0f};
  union { __bf16 h[8]; uint4 u; } pk;
#pragma unroll
  for (int blk = 0; blk < 4; ++blk) {
#pragma unroll
    for (int j = 0; j < 8; ++j) pk.h[j] = (__bf16)(v[blk * 8 + j] * sc);
    *(uint4*)(dst + blk * 8) = pk.u;
  }
}

// ---------------------------------------------------------------------------
// V[bh][t][dh] fp32 -> V^T[bh][dh][t] bf16.
__global__ __launch_bounds__(256)
void prep_vt(const float* __restrict__ Vf, __bf16* __restrict__ Vt) {
  int g = blockIdx.x * 256 + threadIdx.x;     // 0..131071
  int bh = g >> 13, rem = g & 8191;
  int tb = rem >> 5, dh = rem & 31;
  const float* src = Vf + (((size_t)bh * 2048 + tb * 8) * 32) + dh;
  union { __bf16 h[8]; uint4 u; } pk;
#pragma unroll
  for (int e = 0; e < 8; ++e) pk.h[e] = (__bf16)src[e * 32];
  *(uint4*)(Vt + ((size_t)bh * 32 + dh) * 2048 + tb * 8) = pk.u;
}

// ---------------------------------------------------------------------------
// Vsum32[bh][t32][dh] = sum over 32 t of V^T (bf16 values, f32 accumulate).
__global__ __launch_bounds__(256)
void vsum_k(const __bf16* __restrict__ Vt, float* __restrict__ Vsum) {
  int g = blockIdx.x * 256 + threadIdx.x;     // 0..32767
  int bh = g >> 11, rem = g & 2047;
  int t32 = rem >> 5, dh = rem & 31;
  const __bf16* src = Vt + ((size_t)bh * 32 + dh) * 2048 + t32 * 32;
  float s = 0.0f;
#pragma unroll
  for (int i = 0; i < 4; ++i) {
    bf16x8 v = *(const bf16x8*)&src[i * 8];
#pragma unroll
    for (int j = 0; j < 8; ++j) s += (float)v[j];
  }
  Vsum[((size_t)bh * 64 + t32) * 32 + dh] = s;
}

// ---------------------------------------------------------------------------
// Flash attention, clip-shortcut + double-buffered LDS staging.
// Grid (32, 4, 16), 4 waves.
__global__ __launch_bounds__(256)
void attn_mfma(const __bf16* __restrict__ Qbf, const __bf16* __restrict__ Kbf,
               const __bf16* __restrict__ Vt,  const float4* __restrict__ qtab4,
               const float4* __restrict__ ktab4, const float* __restrict__ Vsum,
               float* __restrict__ PN, float* __restrict__ PD) {
  __shared__ __bf16 Kst[2][2048];    // 2 x (64 t x 32 dh), chunk-swizzled
  __shared__ float4 Tst[2][64];      // 2 x (kk, Bk, aLgBk, 0)
  __shared__ __bf16 Pt[4][16][72];   // rare-path per-wave P^T
  const int tid = threadIdx.x;
  const int wid = tid >> 6, lane = tid & 63;
  const int l15 = lane & 15, lg = lane >> 4;
  const int tc = blockIdx.y, bh = blockIdx.z;
  const int sblk = blockIdx.x;
  const int s0 = sblk * 64 + wid * 16;

  bf16x8 qfrag = *(const bf16x8*)(Qbf + ((size_t)bh * 2048 + s0 + l15) * 32 + lg * 8);
  float4 qt = qtab4[bh * 2048 + s0 + l15];
  const float qq = qt.x, Bq = qt.z;
  const float eminRow = EMIN - qt.y;
  const float wclipf = (float)(__bf16)fast_exp2(eminRow);   // bf16-quantized
  float wrow[4];
#pragma unroll
  for (int r = 0; r < 4; ++r)
    wrow[r] = (float)(__bf16)fast_exp2(EMIN - qtab4[bh * 2048 + s0 + lg * 4 + r].y);

  const __bf16* Kbase = Kbf + ((size_t)bh << 16);
  const __bf16* Vbase = Vt + ((size_t)bh << 16);
  const float4* Tbase = ktab4 + bh * 2048;
  const float*  VsBase = Vsum + (size_t)bh * 64 * 32;
  __bf16* Pw = &Pt[wid][0][0];

  f32x4 accO0 = {0.f, 0.f, 0.f, 0.f};
  f32x4 accO1 = {0.f, 0.f, 0.f, 0.f};
  float den = 0.0f;
  const f32x4 zero = {0.f, 0.f, 0.f, 0.f};
  const int tbeg = tc * 512;
  const int stag = sblk & 7;

  const int slot = wid * 64 + lane;          // 16B chunk index 0..255
  const int gch = slot ^ ((slot >> 2) & 3);  // involutive chunk XOR within row

  // prologue: stage tile 0 into buffer 0
  {
    const int t0 = tbeg + ((stag & 7) << 6);
    load_lds16(Kbase + (size_t)t0 * 32 + gch * 8, &Kst[0][wid * 512]);
    if (wid == 0) load_lds16(Tbase + t0 + lane, &Tst[0][0]);
  }
  int cur = 0;

  for (int i = 0; i < 8; ++i) {
    __syncthreads();   // drains stage of buf[cur]; all waves past reads of buf[cur^1]
    if (i < 7) {       // prefetch next tile into the other buffer (overlaps compute)
      const int tn = tbeg + (((i + 1 + stag) & 7) << 6);
      load_lds16(Kbase + (size_t)tn * 32 + gch * 8, &Kst[cur ^ 1][wid * 512]);
      if (wid == 0) load_lds16(Tbase + tn + lane, &Tst[cur ^ 1][0]);
    }
    const int t0 = tbeg + (((i + stag) & 7) << 6);
    const __bf16* Kc = &Kst[cur][0];
    const float4* Tc = &Tst[cur][0];

#pragma unroll
    for (int h = 0; h < 2; ++h) {
      f32x4 S[2];
      bool ok = true;
#pragma unroll
      for (int s2 = 0; s2 < 2; ++s2) {
        const int sub = h * 2 + s2;
        const int R = sub * 16 + l15;
        const int slotR = R * 4 + (lg ^ (R & 3));
        bf16x8 kfrag = *(const bf16x8*)&Kc[slotR * 8];
        f32x4 Sv = __builtin_amdgcn_mfma_f32_16x16x32_bf16(kfrag, qfrag, zero, 0, 0, 0);
        S[s2] = Sv;
        const int tk = sub * 16 + lg * 4;
#pragma unroll
        for (int r = 0; r < 4; ++r) {
          float2 T2 = *(const float2*)&Tc[tk + r];     // (kk, Bk)
          float d = fmaf(qq, T2.x, 1.0f) - (Sv[r] + Sv[r]);
          ok &= (fmaf(-CHI, d, Bq * T2.y) <= 0.0f);
        }
      }
      if (__all((int)ok)) {
        // whole 32-t half clipped: rank-1 update, no PV.
        // den: 4 lanes (lg=0..3) share this q-row and are summed by the
        // lg-reduction below -> each adds 8*wclip so the total is 32*wclip.
        const int ti32 = (t0 >> 5) + h;
        float vsA = VsBase[ti32 * 32 + l15];
        float vsB = VsBase[ti32 * 32 + 16 + l15];
        den += 8.0f * wclipf;
#pragma unroll
        for (int r = 0; r < 4; ++r) {
          accO0[r] = fmaf(wrow[r], vsA, accO0[r]);
          accO1[r] = fmaf(wrow[r], vsB, accO1[r]);
        }
      } else {
        // rare: full exact chain for both subtiles, then PV MFMA (V from global)
#pragma unroll
        for (int s2 = 0; s2 < 2; ++s2) {
          const int sub = h * 2 + s2;
          const int tk = sub * 16 + lg * 4;
          f32x4 Sv = S[s2];
          float w[4];
#pragma unroll
          for (int r = 0; r < 4; ++r) {
            float4 T = Tc[tk + r];                   // kk, Bk, aLgBk
            float qk2 = Sv[r] + Sv[r];
            float u = (qq + T.x) - qk2;
            float d = fmaf(qq, T.x, 1.0f) - qk2;
            float p = fmaxf(u * d, 0.0f);
            float sq = sqrtf(p);
            float m = fmaf(2.0f, sq, u + d);
            float e = fmaf(-ALPHA, fast_log2(m), T.z);
            e = fmaxf(e, eminRow);
            w[r] = fast_exp2(e);
          }
          den += (w[0] + w[1]) + (w[2] + w[3]);
          union { __bf16 hh[4]; uint2 u2; } pk;
          pk.hh[0] = (__bf16)w[0]; pk.hh[1] = (__bf16)w[1];
          pk.hh[2] = (__bf16)w[2]; pk.hh[3] = (__bf16)w[3];
          *(uint2*)&Pw[l15 * 72 + sub * 16 + lg * 4] = pk.u2;
        }
        bf16x8 pfrag = *(const bf16x8*)&Pw[l15 * 72 + h * 32 + lg * 8];
        bf16x8 v0 = *(const bf16x8*)(Vbase + (size_t)l15 * 2048 + t0 + h * 32 + lg * 8);
        bf16x8 v1 = *(const bf16x8*)(Vbase + (size_t)(16 + l15) * 2048 + t0 + h * 32 + lg * 8);
        accO0 = __builtin_amdgcn_mfma_f32_16x16x32_bf16(pfrag, v0, accO0, 0, 0, 0);
        accO1 = __builtin_amdgcn_mfma_f32_16x16x32_bf16(pfrag, v1, accO1, 0, 0, 0);
      }
    }
    cur ^= 1;
  }
  den += __shfl_xor(den, 16);
  den += __shfl_xor(den, 32);
  size_t pbase = ((size_t)tc * 16 + bh) * 2048;
  if (lg == 0) PD[pbase + s0 + l15] = den;
#pragma unroll
  for (int r = 0; r < 4; ++r) {
    int sl = lg * 4 + r;
    size_t row = (pbase + s0 + sl) * 32;
    PN[row + l15]      = accO0[r];
    PN[row + 16 + l15] = accO1[r];
  }
}

// ---------------------------------------------------------------------------
// Sum the 4 t-chunk partials, normalize, write AO as bf16 (h, l) pair.
__global__ __launch_bounds__(256)
void combine4(const float* __restrict__ PN, const float* __restrict__ PD,
              __bf16* __restrict__ AOh, __bf16* __restrict__ AOl) {
  int idx = blockIdx.x * 256 + threadIdx.x;   // 0..32767 = (bh, s)
  int bh = idx >> 11, s = idx & 2047;
  int b = bh >> 3, h = bh & 7;
  float den = 0.0f;
#pragma unroll
  for (int c = 0; c < 4; ++c) den += PD[((size_t)c * 16 + bh) * 2048 + s];
  float r = 1.0f / den;
  size_t ob = ((size_t)b * 2048 + s) * 256 + h * 32;
#pragma unroll
  for (int i = 0; i < 8; ++i) {
    float4 sum = {0.0f, 0.0f, 0.0f, 0.0f};
#pragma unroll
    for (int c = 0; c < 4; ++c) {
      float4 v = *(const float4*)&PN[((((size_t)c * 16 + bh) * 2048 + s) * 32) + i * 4];
      sum.x += v.x; sum.y += v.y; sum.z += v.z; sum.w += v.w;
    }
    float vv[4] = {sum.x * r, sum.y * r, sum.z * r, sum.w * r};
    union { __bf16 h4[4]; uint2 u; } ph, pl;
#pragma unroll
    for (int j = 0; j < 4; ++j) {
      __bf16 hb = (__bf16)vv[j];
      ph.h4[j] = hb;
      pl.h4[j] = (__bf16)(vv[j] - (float)hb);
    }
    *(uint2*)(AOh + ob + i * 4) = ph.u;
    *(uint2*)(AOl + ob + i * 4) = pl.u;
  }
}

// ---------------------------------------------------------------------------
extern "C" void kernel_launch(void* const* d_in, const int* in_sizes, int n_in,
                              void* d_out, int out_size, void* d_ws, size_t ws_size,
                              hipStream_t stream) {
  const float* x   = (const float*)d_in[0];
  const float* Wq  = (const float*)d_in[1];
  const float* bq  = (const float*)d_in[2];
  const float* Wk  = (const float*)d_in[3];
  const float* bk  = (const float*)d_in[4];
  const float* Wv  = (const float*)d_in[5];
  const float* bv  = (const float*)d_in[6];
  const float* Wo  = (const float*)d_in[7];
  const float* bo  = (const float*)d_in[8];
  const float* Wfc = (const float*)d_in[9];
  const float* bfc = (const float*)d_in[10];

  float* ws = (float*)d_ws;
  // Workspace layout (float offsets); total 10.375M floats = 41.5 MB.
  float* Qb  = ws;                                      // 1M
  float* Kb  = ws + (1 << 20);                          // 1M
  float* Vb  = ws + (2 << 20);                          // 1M
  __bf16* Qbf = (__bf16*)(ws + (3 << 20));              // 1M bf16
  __bf16* Kbf = (__bf16*)(ws + (3 << 20) + (1 << 19));  // 1M bf16
  __bf16* Vtb = (__bf16*)(ws + (4 << 20));              // 1M bf16
  float4* qtab4 = (float4*)(ws + (4 << 20) + (1 << 19));             // 128K f
  float4* ktab4 = (float4*)(ws + (4 << 20) + (1 << 19) + (1 << 17)); // 128K f
  float*  Vsum  = ws + (4 << 20) + (1 << 19) + (2 << 17);            // 32K f
  __bf16* Wch   = (__bf16*)(ws + (4 << 20) + (1 << 19) + (2 << 17) + (1 << 15)); // 64K bf16
  __bf16* Wcl   = Wch + 65536;                                        // 64K bf16
  float*  bcomb = ws + (4 << 20) + (1 << 19) + (2 << 17) + (1 << 15) + (1 << 16); // 256
  __bf16* xh = (__bf16*)(ws + (5 << 20));               // 1M bf16
  __bf16* xl = (__bf16*)(ws + (5 << 20) + (1 << 19));   // 1M bf16
  __bf16* Wsplit = (__bf16*)(ws + (6 << 20));           // 393216 bf16
  float* PN = ws + (6 << 20) + (1 << 18);               // 4M
  float* PD = PN + (4 << 20);                           // 128K
  __bf16* AOh = (__bf16*)ws;                            // reuse Qb slab
  __bf16* AOl = (__bf16*)(ws + (1 << 19));              // reuse Qb slab

  dim3 blk(256);
  split_all<<<dim3(608), blk, 0, stream>>>(x, Wq, Wk, Wv, xh, xl, Wsplit);
  gemm_qkv_mfma<<<dim3(64, 12), blk, 0, stream>>>(xh, xl, Wsplit, bq, bk, bv, Qb, Kb, Vb);
  prep_qk<<<dim3(256), blk, 0, stream>>>(Qb, Kb, Qbf, Kbf, qtab4, ktab4);
  prep_vt<<<dim3(512), blk, 0, stream>>>(Vb, Vtb);
  vsum_k<<<dim3(128), blk, 0, stream>>>(Vtb, Vsum);
  gemm_nn_small<<<dim3(4, 4), blk, 0, stream>>>(Wfc, Wo, Wch, Wcl);
  bcomb_k<<<dim3(16), blk, 0, stream>>>(Wfc, bo, bfc, bcomb);
  attn_mfma<<<dim3(32, 4, 16), blk, 0, stream>>>(Qbf, Kbf, Vtb, qtab4, ktab4, Vsum, PN, PD);
  combine4<<<dim3(128), blk, 0, stream>>>(PN, PD, AOh, AOl);
  gemm_out_mfma<<<dim3(64, 4), blk, 0, stream>>>(AOh, AOl, Wch, Wcl, bcomb, (float*)d_out);
}

// Round 10
// 109.633 us; speedup vs baseline: 1.1250x; 1.1250x over previous
//
#include <hip/hip_runtime.h>
#include <cstdint>
#include <cstddef>

// Poincare-ball (hyperbolic) attention block. B=2, S=2048, D=256, H=8, dh=32, c=1.
//
// Round 10:
//  - attn clip test collapsed to a per-row conservative scalar: thr_all =
//    0.5 + (qq/2)*kkmin - Bq*Bkmax/(2*CHI); subtile test = max(S) <= thr_all
//    (3 fmax + 1 cmp per 16 pairs). Tst staging removed; rare fallback reads
//    ktab4 from L2 and is identical to the proven round-8 exact chain.
//  - kkmin/Bkmax per bh: free LDS reduction in prep_qk's K-blocks -> Kred[128].
//  - kernels fused 10 -> 6: K1 = wcomb+bcomb+splits, K3 = prep_qk+prep_vt+vsum
//    (vsum reads fp32 V directly).

#define ALPHA 0.17677669529663687f   // 1/sqrt(32)
#define EMIN  -3.1129694f            // -ALPHA * log2((2-1e-5)/1e-5)  (clip)
#define CHI   1.95e-5f               // conservative 1-(1-1e-5)^2
#define NEG_INV_2CHI -25641.026f     // -1/(2*CHI)

typedef __bf16 bf16x8 __attribute__((ext_vector_type(8)));
typedef float  f32x4  __attribute__((ext_vector_type(4)));

__device__ __forceinline__ float fast_log2(float x) { return __builtin_amdgcn_logf(x); }
__device__ __forceinline__ float fast_exp2(float x) { return __builtin_amdgcn_exp2f(x); }

__device__ __forceinline__ void load_lds16(const void* g, void* l) {
  __builtin_amdgcn_global_load_lds((const __attribute__((address_space(1))) void*)g,
                                   (__attribute__((address_space(3))) void*)l, 16, 0, 0);
}

// ---------------------------------------------------------------------------
// K1: fused {Wcomb = Wfc@Wo (blocks 0-15)} {bcomb = Wfc@bo+bfc (16-31)}
//     {fp32->bf16 h/l splits of x, Wq, Wk, Wv (32-639)}.
__global__ __launch_bounds__(256)
void k1_misc(const float* __restrict__ x,   const float* __restrict__ Wq,
             const float* __restrict__ Wk,  const float* __restrict__ Wv,
             const float* __restrict__ Wfc, const float* __restrict__ Wo,
             const float* __restrict__ bo,  const float* __restrict__ bfc,
             __bf16* __restrict__ xh, __bf16* __restrict__ xl,
             __bf16* __restrict__ Ws, __bf16* __restrict__ Wch,
             __bf16* __restrict__ Wcl, float* __restrict__ bcomb) {
  __shared__ float sh[2 * 32 * 68];
  const int bx = blockIdx.x, tid = threadIdx.x;
  if (bx < 16) {
    // ---- Wcomb = Wfc @ Wo (NN, 256^3), fp32, bf16 h/l out ----
    float (*AsT)[68] = (float(*)[68])sh;
    float (*Bs)[68]  = (float(*)[68])(sh + 32 * 68);
    const int ty = tid >> 4, tx = tid & 15;
    const int m0 = (bx >> 2) * 64, n0 = (bx & 3) * 64;
    float acc[4][4] = {};
    for (int k0 = 0; k0 < 256; k0 += 32) {
#pragma unroll
      for (int jj = 0; jj < 2; ++jj) {
        int j = tid * 2 + jj;
        {
          int r = j >> 3, c4 = (j & 7) << 2;
          float4 av = *(const float4*)&Wfc[(size_t)(m0 + r) * 256 + k0 + c4];
          AsT[c4 + 0][r] = av.x; AsT[c4 + 1][r] = av.y;
          AsT[c4 + 2][r] = av.z; AsT[c4 + 3][r] = av.w;
        }
        {
          int r = j >> 4, c4 = (j & 15) << 2;
          *(float4*)&Bs[r][c4] = *(const float4*)&Wo[(size_t)(k0 + r) * 256 + n0 + c4];
        }
      }
      __syncthreads();
#pragma unroll
      for (int kk = 0; kk < 32; ++kk) {
        float4 a = *(const float4*)&AsT[kk][ty * 4];
        float4 b = *(const float4*)&Bs[kk][tx * 4];
        float av[4] = {a.x, a.y, a.z, a.w};
        float bv[4] = {b.x, b.y, b.z, b.w};
#pragma unroll
        for (int i = 0; i < 4; ++i)
#pragma unroll
          for (int j2 = 0; j2 < 4; ++j2)
            acc[i][j2] = fmaf(av[i], bv[j2], acc[i][j2]);
      }
      __syncthreads();
    }
#pragma unroll
    for (int i = 0; i < 4; ++i) {
      union { __bf16 h[4]; uint2 u; } ph, pl;
#pragma unroll
      for (int j = 0; j < 4; ++j) {
        __bf16 hb = (__bf16)acc[i][j];
        ph.h[j] = hb;
        pl.h[j] = (__bf16)(acc[i][j] - (float)hb);
      }
      size_t off = (size_t)(m0 + ty * 4 + i) * 256 + n0 + tx * 4;
      *(uint2*)(Wch + off) = ph.u;
      *(uint2*)(Wcl + off) = pl.u;
    }
  } else if (bx < 32) {
    // ---- bcomb = Wfc @ bo + bfc ----
    float* red = sh;
    int r = tid >> 4, c = tid & 15;
    int row = (bx - 16) * 16 + r;
    float s = 0.0f;
    for (int k = c; k < 256; k += 16) s = fmaf(Wfc[(size_t)row * 256 + k], bo[k], s);
    red[tid] = s;
    __syncthreads();
    if (c == 0) {
      float t = 0.0f;
#pragma unroll
      for (int i = 0; i < 16; ++i) t += red[r * 16 + i];
      bcomb[row] = t + bfc[row];
    }
  } else {
    // ---- split fp32 -> bf16 h + residual l ----
    int g = (bx - 32) * 256 + tid;
    const float* src;
    __bf16 *dh, *dl;
    if (g < 131072) {                     // x: 1,048,576 floats
      src = x + (size_t)g * 8; dh = xh + (size_t)g * 8; dl = xl + (size_t)g * 8;
    } else {
      int e = g - 131072;                 // 0..24575
      int wsel = e >> 13;
      int inner = (e & 8191) * 8;
      src = (wsel == 0 ? Wq : (wsel == 1 ? Wk : Wv)) + inner;
      dh = Ws + wsel * 131072 + inner;
      dl = Ws + wsel * 131072 + 65536 + inner;
    }
    union { __bf16 h[8]; uint4 u; } ph, pl;
#pragma unroll
    for (int i = 0; i < 2; ++i) {
      float4 v = *(const float4*)(src + i * 4);
      float vv[4] = {v.x, v.y, v.z, v.w};
#pragma unroll
      for (int j = 0; j < 4; ++j) {
        __bf16 hb = (__bf16)vv[j];
        ph.h[i * 4 + j] = hb;
        pl.h[i * 4 + j] = (__bf16)(vv[j] - (float)hb);
      }
    }
    *(uint4*)dh = ph.u;
    *(uint4*)dl = pl.u;
  }
}

// ---------------------------------------------------------------------------
// Fused QKV projection, split-bf16 MFMA. Grid (64, 12), 4 waves.
__global__ __launch_bounds__(256)
void gemm_qkv_mfma(const __bf16* __restrict__ xh, const __bf16* __restrict__ xl,
                   const __bf16* __restrict__ Ws,
                   const float* __restrict__ bq, const float* __restrict__ bk,
                   const float* __restrict__ bv,
                   float* __restrict__ Qb, float* __restrict__ Kb,
                   float* __restrict__ Vb) {
  const int tid = threadIdx.x, w = tid >> 6, lane = tid & 63;
  const int l15 = lane & 15, lg = lane >> 4;
  const int m0 = blockIdx.x * 64, nb = blockIdx.y;
  const int wsel = nb >> 2;
  const int n256b = (nb & 3) * 64;
  const __bf16* Wh = Ws + wsel * 131072;
  const __bf16* Wl = Wh + 65536;
  const int arow = m0 + w * 16 + l15;
  const __bf16* axh = xh + (size_t)arow * 256 + lg * 8;
  const __bf16* axl = xl + (size_t)arow * 256 + lg * 8;
  f32x4 acc0 = {0,0,0,0}, acc1 = {0,0,0,0}, acc2 = {0,0,0,0}, acc3 = {0,0,0,0};
#pragma unroll
  for (int k0 = 0; k0 < 256; k0 += 32) {
    bf16x8 ah = *(const bf16x8*)(axh + k0);
    bf16x8 al = *(const bf16x8*)(axl + k0);
#pragma unroll
    for (int g = 0; g < 4; ++g) {
      const size_t br = (size_t)(n256b + g * 16 + l15) * 256 + lg * 8 + k0;
      bf16x8 bh = *(const bf16x8*)(Wh + br);
      bf16x8 bl = *(const bf16x8*)(Wl + br);
      f32x4& acc = g == 0 ? acc0 : (g == 1 ? acc1 : (g == 2 ? acc2 : acc3));
      acc = __builtin_amdgcn_mfma_f32_16x16x32_bf16(ah, bh, acc, 0, 0, 0);
      acc = __builtin_amdgcn_mfma_f32_16x16x32_bf16(al, bh, acc, 0, 0, 0);
      acc = __builtin_amdgcn_mfma_f32_16x16x32_bf16(ah, bl, acc, 0, 0, 0);
    }
  }
  const float* bias = wsel == 0 ? bq : (wsel == 1 ? bk : bv);
  float* C = wsel == 0 ? Qb : (wsel == 1 ? Kb : Vb);
#pragma unroll
  for (int g = 0; g < 4; ++g) {
    const f32x4& acc = g == 0 ? acc0 : (g == 1 ? acc1 : (g == 2 ? acc2 : acc3));
    int n256 = n256b + g * 16 + l15;
    float bval = bias[n256];
    int h = n256 >> 5, d = n256 & 31;
#pragma unroll
    for (int r = 0; r < 4; ++r) {
      int m = m0 + w * 16 + lg * 4 + r;
      int b = m >> 11, s = m & 2047;
      C[((size_t)((b << 3) + h) << 16) + (size_t)s * 32 + d] = acc[r] + bval;
    }
  }
}

// ---------------------------------------------------------------------------
// K3: fused {prep_qk (blocks 0-255, K-blocks also reduce kkmin/Bkmax)}
//     {prep_vt (256-767)} {vsum from fp32 V (768-895)}.
__global__ __launch_bounds__(256)
void k3_prep(const float* __restrict__ Qf, const float* __restrict__ Kf,
             const float* __restrict__ Vf,
             __bf16* __restrict__ Qbf, __bf16* __restrict__ Kbf,
             __bf16* __restrict__ Vt,
             float4* __restrict__ qtab4, float4* __restrict__ ktab4,
             float* __restrict__ Vsum, float2* __restrict__ Kred) {
  __shared__ float2 red2[256];
  const int bx = blockIdx.x, tid = threadIdx.x;
  if (bx < 256) {
    // ---- expmap0 -> bf16 rows + tables ----
    int idx = bx * 256 + tid;                 // 0..65535
    const bool isQ = idx < 32768;
    const int i2 = isQ ? idx : idx - 32768;
    const float* src = (isQ ? Qf : Kf) + (size_t)i2 * 32;
    __bf16* dst = (isQ ? Qbf : Kbf) + (size_t)i2 * 32;
    float v[32];
    float ss = 0.0f;
#pragma unroll
    for (int i = 0; i < 8; ++i) {
      float4 v4 = *(const float4*)&src[i * 4];
      v[i*4+0] = v4.x; v[i*4+1] = v4.y; v[i*4+2] = v4.z; v[i*4+3] = v4.w;
      ss = fmaf(v4.x, v4.x, ss); ss = fmaf(v4.y, v4.y, ss);
      ss = fmaf(v4.z, v4.z, ss); ss = fmaf(v4.w, v4.w, ss);
    }
    ss = fmaxf(ss, 1e-12f);
    float x  = sqrtf(ss);
    float ex = fast_exp2(-2.8853900817779268f * x);     // e^{-2x}
    float opex = 1.0f + ex;
    float th = (1.0f - ex) / opex;
    float sc = th / x;
    float qq = th * th;
    float Bv = 4.0f * ex / (opex * opex);                // 1 - qq, exact
    float lgB = 2.0f - 2.8853900817779268f * x - 2.0f * fast_log2(opex);
    if (isQ) qtab4[i2] = float4{qq, ALPHA * lgB, Bv, 0.0f};
    else     ktab4[i2] = float4{qq, Bv, ALPHA * lgB, 0.0f};
    union { __bf16 h[8]; uint4 u; } pk;
#pragma unroll
    for (int blk = 0; blk < 4; ++blk) {
#pragma unroll
      for (int j = 0; j < 8; ++j) pk.h[j] = (__bf16)(v[blk * 8 + j] * sc);
      *(uint4*)(dst + blk * 8) = pk.u;
    }
    if (!isQ) {   // block-uniform: blocks 128..255 are all-K
      red2[tid] = float2{qq, Bv};
      __syncthreads();
      for (int s = 128; s > 0; s >>= 1) {
        if (tid < s) {
          red2[tid].x = fminf(red2[tid].x, red2[tid + s].x);
          red2[tid].y = fmaxf(red2[tid].y, red2[tid + s].y);
        }
        __syncthreads();
      }
      if (tid == 0) Kred[bx - 128] = red2[0];  // 8 partials per bh
    }
  } else if (bx < 768) {
    // ---- V[bh][t][dh] fp32 -> V^T[bh][dh][t] bf16 ----
    int g = (bx - 256) * 256 + tid;           // 0..131071
    int bh = g >> 13, rem = g & 8191;
    int tb = rem >> 5, dh = rem & 31;
    const float* src = Vf + (((size_t)bh * 2048 + tb * 8) * 32) + dh;
    union { __bf16 h[8]; uint4 u; } pk;
#pragma unroll
    for (int e = 0; e < 8; ++e) pk.h[e] = (__bf16)src[e * 32];
    *(uint4*)(Vt + ((size_t)bh * 32 + dh) * 2048 + tb * 8) = pk.u;
  } else {
    // ---- Vsum32[bh][t32][dh] = sum_{j<32} V[bh][t32*32+j][dh] (fp32) ----
    int g = (bx - 768) * 256 + tid;           // 0..32767
    int bh = g >> 11, rem = g & 2047;
    int t32 = rem >> 5, dh = rem & 31;
    const float* src = Vf + (((size_t)bh * 2048 + t32 * 32) * 32) + dh;
    float s = 0.0f;
#pragma unroll
    for (int j = 0; j < 32; ++j) s += src[j * 32];
    Vsum[((size_t)bh * 64 + t32) * 32 + dh] = s;
  }
}

// ---------------------------------------------------------------------------
// Flash attention, scalar-conservative clip test + double-buffered K staging.
// Grid (32, 4, 16), 4 waves.
__global__ __launch_bounds__(256)
void attn_mfma(const __bf16* __restrict__ Qbf, const __bf16* __restrict__ Kbf,
               const __bf16* __restrict__ Vt,  const float4* __restrict__ qtab4,
               const float4* __restrict__ ktab4, const float* __restrict__ Vsum,
               const float2* __restrict__ Kred,
               float* __restrict__ PN, float* __restrict__ PD) {
  __shared__ __bf16 Kst[2][2048];    // 2 x (64 t x 32 dh), chunk-swizzled
  __shared__ __bf16 Pt[4][16][72];   // rare-path per-wave P^T
  const int tid = threadIdx.x;
  const int wid = tid >> 6, lane = tid & 63;
  const int l15 = lane & 15, lg = lane >> 4;
  const int tc = blockIdx.y, bh = blockIdx.z;
  const int sblk = blockIdx.x;
  const int s0 = sblk * 64 + wid * 16;

  bf16x8 qfrag = *(const bf16x8*)(Qbf + ((size_t)bh * 2048 + s0 + l15) * 32 + lg * 8);
  float4 qt = qtab4[bh * 2048 + s0 + l15];
  const float qq = qt.x, Bq = qt.z;
  const float eminRow = EMIN - qt.y;
  const float wclipf = (float)(__bf16)fast_exp2(eminRow);   // bf16-quantized
  float wrow[4];
#pragma unroll
  for (int r = 0; r < 4; ++r)
    wrow[r] = (float)(__bf16)fast_exp2(EMIN - qtab4[bh * 2048 + s0 + lg * 4 + r].y);

  // conservative per-row clip threshold: max(S) <= thr_all => whole subtile clips
  float kkmin = 1.0f, bkmax = 0.0f;
#pragma unroll
  for (int j = 0; j < 8; ++j) {
    float2 kr = Kred[bh * 8 + j];
    kkmin = fminf(kkmin, kr.x);
    bkmax = fmaxf(bkmax, kr.y);
  }
  const float thr_all = fmaf(0.5f * qq, kkmin,
                             fmaf(Bq * NEG_INV_2CHI, bkmax, 0.5f));

  const __bf16* Kbase = Kbf + ((size_t)bh << 16);
  const __bf16* Vbase = Vt + ((size_t)bh << 16);
  const float4* Tk = ktab4 + bh * 2048;
  const float*  VsBase = Vsum + (size_t)bh * 64 * 32;
  __bf16* Pw = &Pt[wid][0][0];

  f32x4 accO0 = {0.f, 0.f, 0.f, 0.f};
  f32x4 accO1 = {0.f, 0.f, 0.f, 0.f};
  float den = 0.0f;
  const f32x4 zero = {0.f, 0.f, 0.f, 0.f};
  const int tbeg = tc * 512;
  const int stag = sblk & 7;

  const int slot = wid * 64 + lane;          // 16B chunk index 0..255
  const int gch = slot ^ ((slot >> 2) & 3);  // involutive chunk XOR within row

  {  // prologue: stage tile 0 into buffer 0
    const int t0 = tbeg + ((stag & 7) << 6);
    load_lds16(Kbase + (size_t)t0 * 32 + gch * 8, &Kst[0][wid * 512]);
  }
  int cur = 0;

  for (int i = 0; i < 8; ++i) {
    __syncthreads();   // stage of buf[cur] drained; reads of buf[cur^1] done
    if (i < 7) {
      const int tn = tbeg + (((i + 1 + stag) & 7) << 6);
      load_lds16(Kbase + (size_t)tn * 32 + gch * 8, &Kst[cur ^ 1][wid * 512]);
    }
    const int t0 = tbeg + (((i + stag) & 7) << 6);
    const __bf16* Kc = &Kst[cur][0];

#pragma unroll
    for (int h = 0; h < 2; ++h) {
      f32x4 S[2];
      bool ok = true;
#pragma unroll
      for (int s2 = 0; s2 < 2; ++s2) {
        const int sub = h * 2 + s2;
        const int R = sub * 16 + l15;
        const int slotR = R * 4 + (lg ^ (R & 3));
        bf16x8 kfrag = *(const bf16x8*)&Kc[slotR * 8];
        f32x4 Sv = __builtin_amdgcn_mfma_f32_16x16x32_bf16(kfrag, qfrag, zero, 0, 0, 0);
        S[s2] = Sv;
        float m = fmaxf(fmaxf(Sv[0], Sv[1]), fmaxf(Sv[2], Sv[3]));
        ok &= (m <= thr_all);
      }
      if (__all((int)ok)) {
        // whole 32-t half clipped: rank-1 update, no PV.
        // 4 lanes (lg) share this q-row and are summed below -> 8*wclip each.
        const int ti32 = (t0 >> 5) + h;
        float vsA = VsBase[ti32 * 32 + l15];
        float vsB = VsBase[ti32 * 32 + 16 + l15];
        den += 8.0f * wclipf;
#pragma unroll
        for (int r = 0; r < 4; ++r) {
          accO0[r] = fmaf(wrow[r], vsA, accO0[r]);
          accO1[r] = fmaf(wrow[r], vsB, accO1[r]);
        }
      } else {
        // rare: exact chain for both subtiles (ktab4 from L2), PV MFMA
#pragma unroll
        for (int s2 = 0; s2 < 2; ++s2) {
          const int sub = h * 2 + s2;
          const int tk = t0 + sub * 16 + lg * 4;
          f32x4 Sv = S[s2];
          float w[4];
#pragma unroll
          for (int r = 0; r < 4; ++r) {
            float4 T = Tk[tk + r];                   // kk, Bk, aLgBk
            float qk2 = Sv[r] + Sv[r];
            float u = (qq + T.x) - qk2;
            float d = fmaf(qq, T.x, 1.0f) - qk2;
            float p = fmaxf(u * d, 0.0f);
            float sq = sqrtf(p);
            float m = fmaf(2.0f, sq, u + d);
            float e = fmaf(-ALPHA, fast_log2(m), T.z);
            e = fmaxf(e, eminRow);
            w[r] = fast_exp2(e);
          }
          den += (w[0] + w[1]) + (w[2] + w[3]);
          union { __bf16 hh[4]; uint2 u2; } pk;
          pk.hh[0] = (__bf16)w[0]; pk.hh[1] = (__bf16)w[1];
          pk.hh[2] = (__bf16)w[2]; pk.hh[3] = (__bf16)w[3];
          *(uint2*)&Pw[l15 * 72 + sub * 16 + lg * 4] = pk.u2;
        }
        bf16x8 pfrag = *(const bf16x8*)&Pw[l15 * 72 + h * 32 + lg * 8];
        bf16x8 v0 = *(const bf16x8*)(Vbase + (size_t)l15 * 2048 + t0 + h * 32 + lg * 8);
        bf16x8 v1 = *(const bf16x8*)(Vbase + (size_t)(16 + l15) * 2048 + t0 + h * 32 + lg * 8);
        accO0 = __builtin_amdgcn_mfma_f32_16x16x32_bf16(pfrag, v0, accO0, 0, 0, 0);
        accO1 = __builtin_amdgcn_mfma_f32_16x16x32_bf16(pfrag, v1, accO1, 0, 0, 0);
      }
    }
    cur ^= 1;
  }
  den += __shfl_xor(den, 16);
  den += __shfl_xor(den, 32);
  size_t pbase = ((size_t)tc * 16 + bh) * 2048;
  if (lg == 0) PD[pbase + s0 + l15] = den;
#pragma unroll
  for (int r = 0; r < 4; ++r) {
    int sl = lg * 4 + r;
    size_t row = (pbase + s0 + sl) * 32;
    PN[row + l15]      = accO0[r];
    PN[row + 16 + l15] = accO1[r];
  }
}

// ---------------------------------------------------------------------------
// Sum the 4 t-chunk partials, normalize, write AO as bf16 (h, l) pair.
__global__ __launch_bounds__(256)
void combine4(const float* __restrict__ PN, const float* __restrict__ PD,
              __bf16* __restrict__ AOh, __bf16* __restrict__ AOl) {
  int idx = blockIdx.x * 256 + threadIdx.x;   // 0..32767 = (bh, s)
  int bh = idx >> 11, s = idx & 2047;
  int b = bh >> 3, h = bh & 7;
  float den = 0.0f;
#pragma unroll
  for (int c = 0; c < 4; ++c) den += PD[((size_t)c * 16 + bh) * 2048 + s];
  float r = 1.0f / den;
  size_t ob = ((size_t)b * 2048 + s) * 256 + h * 32;
#pragma unroll
  for (int i = 0; i < 8; ++i) {
    float4 sum = {0.0f, 0.0f, 0.0f, 0.0f};
#pragma unroll
    for (int c = 0; c < 4; ++c) {
      float4 v = *(const float4*)&PN[((((size_t)c * 16 + bh) * 2048 + s) * 32) + i * 4];
      sum.x += v.x; sum.y += v.y; sum.z += v.z; sum.w += v.w;
    }
    float vv[4] = {sum.x * r, sum.y * r, sum.z * r, sum.w * r};
    union { __bf16 h4[4]; uint2 u; } ph, pl;
#pragma unroll
    for (int j = 0; j < 4; ++j) {
      __bf16 hb = (__bf16)vv[j];
      ph.h4[j] = hb;
      pl.h4[j] = (__bf16)(vv[j] - (float)hb);
    }
    *(uint2*)(AOh + ob + i * 4) = ph.u;
    *(uint2*)(AOl + ob + i * 4) = pl.u;
  }
}

// ---------------------------------------------------------------------------
// Output projection, split-bf16 MFMA: out = AO @ Wcomb^T + bcomb. Grid (64,4).
__global__ __launch_bounds__(256)
void gemm_out_mfma(const __bf16* __restrict__ aoh, const __bf16* __restrict__ aol,
                   const __bf16* __restrict__ Wch, const __bf16* __restrict__ Wcl,
                   const float* __restrict__ bcomb, float* __restrict__ out) {
  const int tid = threadIdx.x, w = tid >> 6, lane = tid & 63;
  const int l15 = lane & 15, lg = lane >> 4;
  const int m0 = blockIdx.x * 64, n0 = blockIdx.y * 64;
  const int arow = m0 + w * 16 + l15;
  const __bf16* axh = aoh + (size_t)arow * 256 + lg * 8;
  const __bf16* axl = aol + (size_t)arow * 256 + lg * 8;
  f32x4 acc0 = {0,0,0,0}, acc1 = {0,0,0,0}, acc2 = {0,0,0,0}, acc3 = {0,0,0,0};
#pragma unroll
  for (int k0 = 0; k0 < 256; k0 += 32) {
    bf16x8 ah = *(const bf16x8*)(axh + k0);
    bf16x8 al = *(const bf16x8*)(axl + k0);
#pragma unroll
    for (int g = 0; g < 4; ++g) {
      const size_t br = (size_t)(n0 + g * 16 + l15) * 256 + lg * 8 + k0;
      bf16x8 bh = *(const bf16x8*)(Wch + br);
      bf16x8 bl = *(const bf16x8*)(Wcl + br);
      f32x4& acc = g == 0 ? acc0 : (g == 1 ? acc1 : (g == 2 ? acc2 : acc3));
      acc = __builtin_amdgcn_mfma_f32_16x16x32_bf16(ah, bh, acc, 0, 0, 0);
      acc = __builtin_amdgcn_mfma_f32_16x16x32_bf16(al, bh, acc, 0, 0, 0);
      acc = __builtin_amdgcn_mfma_f32_16x16x32_bf16(ah, bl, acc, 0, 0, 0);
    }
  }
#pragma unroll
  for (int g = 0; g < 4; ++g) {
    const f32x4& acc = g == 0 ? acc0 : (g == 1 ? acc1 : (g == 2 ? acc2 : acc3));
    int n = n0 + g * 16 + l15;
    float bval = bcomb[n];
#pragma unroll
    for (int r = 0; r < 4; ++r) {
      int m = m0 + w * 16 + lg * 4 + r;
      out[(size_t)m * 256 + n] = acc[r] + bval;
    }
  }
}

// ---------------------------------------------------------------------------
extern "C" void kernel_launch(void* const* d_in, const int* in_sizes, int n_in,
                              void* d_out, int out_size, void* d_ws, size_t ws_size,
                              hipStream_t stream) {
  const float* x   = (const float*)d_in[0];
  const float* Wq  = (const float*)d_in[1];
  const float* bq  = (const float*)d_in[2];
  const float* Wk  = (const float*)d_in[3];
  const float* bk  = (const float*)d_in[4];
  const float* Wv  = (const float*)d_in[5];
  const float* bv  = (const float*)d_in[6];
  const float* Wo  = (const float*)d_in[7];
  const float* bo  = (const float*)d_in[8];
  const float* Wfc = (const float*)d_in[9];
  const float* bfc = (const float*)d_in[10];

  float* ws = (float*)d_ws;
  // Workspace layout (float offsets); ~41.7 MB total.
  float* Qb  = ws;                                      // 1M
  float* Kb  = ws + (1 << 20);                          // 1M
  float* Vb  = ws + (2 << 20);                          // 1M
  __bf16* Qbf = (__bf16*)(ws + (3 << 20));              // 1M bf16
  __bf16* Kbf = (__bf16*)(ws + (3 << 20) + (1 << 19));  // 1M bf16
  __bf16* Vtb = (__bf16*)(ws + (4 << 20));              // 1M bf16
  float4* qtab4 = (float4*)(ws + (4 << 20) + (1 << 19));             // 128K f
  float4* ktab4 = (float4*)(ws + (4 << 20) + (1 << 19) + (1 << 17)); // 128K f
  float*  Vsum  = ws + (4 << 20) + (1 << 19) + (2 << 17);            // 32K f
  __bf16* Wch   = (__bf16*)(Vsum + (1 << 15));          // 64K bf16 (32K f)
  __bf16* Wcl   = Wch + 65536;                          // 64K bf16
  float*  bcomb = Vsum + (1 << 15) + (1 << 16);         // 256
  float2* Kred  = (float2*)(bcomb + 256);               // 128 float2
  __bf16* xh = (__bf16*)(ws + (5 << 20));               // 1M bf16
  __bf16* xl = (__bf16*)(ws + (5 << 20) + (1 << 19));   // 1M bf16
  __bf16* Wsplit = (__bf16*)(ws + (6 << 20));           // 393216 bf16
  float* PN = ws + (6 << 20) + (1 << 18);               // 4M
  float* PD = PN + (4 << 20);                           // 128K
  __bf16* AOh = (__bf16*)ws;                            // reuse Qb slab
  __bf16* AOl = (__bf16*)(ws + (1 << 19));              // reuse Qb slab

  dim3 blk(256);
  k1_misc<<<dim3(640), blk, 0, stream>>>(x, Wq, Wk, Wv, Wfc, Wo, bo, bfc,
                                         xh, xl, Wsplit, Wch, Wcl, bcomb);
  gemm_qkv_mfma<<<dim3(64, 12), blk, 0, stream>>>(xh, xl, Wsplit, bq, bk, bv,
                                                  Qb, Kb, Vb);
  k3_prep<<<dim3(896), blk, 0, stream>>>(Qb, Kb, Vb, Qbf, Kbf, Vtb,
                                         qtab4, ktab4, Vsum, Kred);
  attn_mfma<<<dim3(32, 4, 16), blk, 0, stream>>>(Qbf, Kbf, Vtb, qtab4, ktab4,
                                                 Vsum, Kred, PN, PD);
  combine4<<<dim3(128), blk, 0, stream>>>(PN, PD, AOh, AOl);
  gemm_out_mfma<<<dim3(64, 4), blk, 0, stream>>>(AOh, AOl, Wch, Wcl, bcomb,
                                                 (float*)d_out);
}

// Round 11
// 108.291 us; speedup vs baseline: 1.1390x; 1.0124x over previous
//
#include <hip/hip_runtime.h>
#include <cstdint>
#include <cstddef>

// Poincare-ball (hyperbolic) attention block. B=2, S=2048, D=256, H=8, dh=32, c=1.
//
// Round 11 (attn_mfma only, vs round 10):
//  - Vsum loads hoisted to tile-start (unconditional, address depends only on
//    t0) -> kills the branch-dependent ~200cy L2 latency per half-tile that
//    dominated the per-tile critical path.
//  - fast-path den accumulated as an integer count, folded once at the end.
//  - s_setprio(1) around the MFMA + clip-test region (T5).

#define ALPHA 0.17677669529663687f   // 1/sqrt(32)
#define EMIN  -3.1129694f            // -ALPHA * log2((2-1e-5)/1e-5)  (clip)
#define CHI   1.95e-5f               // conservative 1-(1-1e-5)^2
#define NEG_INV_2CHI -25641.026f     // -1/(2*CHI)

typedef __bf16 bf16x8 __attribute__((ext_vector_type(8)));
typedef float  f32x4  __attribute__((ext_vector_type(4)));

__device__ __forceinline__ float fast_log2(float x) { return __builtin_amdgcn_logf(x); }
__device__ __forceinline__ float fast_exp2(float x) { return __builtin_amdgcn_exp2f(x); }

__device__ __forceinline__ void load_lds16(const void* g, void* l) {
  __builtin_amdgcn_global_load_lds((const __attribute__((address_space(1))) void*)g,
                                   (__attribute__((address_space(3))) void*)l, 16, 0, 0);
}

// ---------------------------------------------------------------------------
// K1: fused {Wcomb = Wfc@Wo (blocks 0-15)} {bcomb = Wfc@bo+bfc (16-31)}
//     {fp32->bf16 h/l splits of x, Wq, Wk, Wv (32-639)}.
__global__ __launch_bounds__(256)
void k1_misc(const float* __restrict__ x,   const float* __restrict__ Wq,
             const float* __restrict__ Wk,  const float* __restrict__ Wv,
             const float* __restrict__ Wfc, const float* __restrict__ Wo,
             const float* __restrict__ bo,  const float* __restrict__ bfc,
             __bf16* __restrict__ xh, __bf16* __restrict__ xl,
             __bf16* __restrict__ Ws, __bf16* __restrict__ Wch,
             __bf16* __restrict__ Wcl, float* __restrict__ bcomb) {
  __shared__ float sh[2 * 32 * 68];
  const int bx = blockIdx.x, tid = threadIdx.x;
  if (bx < 16) {
    // ---- Wcomb = Wfc @ Wo (NN, 256^3), fp32, bf16 h/l out ----
    float (*AsT)[68] = (float(*)[68])sh;
    float (*Bs)[68]  = (float(*)[68])(sh + 32 * 68);
    const int ty = tid >> 4, tx = tid & 15;
    const int m0 = (bx >> 2) * 64, n0 = (bx & 3) * 64;
    float acc[4][4] = {};
    for (int k0 = 0; k0 < 256; k0 += 32) {
#pragma unroll
      for (int jj = 0; jj < 2; ++jj) {
        int j = tid * 2 + jj;
        {
          int r = j >> 3, c4 = (j & 7) << 2;
          float4 av = *(const float4*)&Wfc[(size_t)(m0 + r) * 256 + k0 + c4];
          AsT[c4 + 0][r] = av.x; AsT[c4 + 1][r] = av.y;
          AsT[c4 + 2][r] = av.z; AsT[c4 + 3][r] = av.w;
        }
        {
          int r = j >> 4, c4 = (j & 15) << 2;
          *(float4*)&Bs[r][c4] = *(const float4*)&Wo[(size_t)(k0 + r) * 256 + n0 + c4];
        }
      }
      __syncthreads();
#pragma unroll
      for (int kk = 0; kk < 32; ++kk) {
        float4 a = *(const float4*)&AsT[kk][ty * 4];
        float4 b = *(const float4*)&Bs[kk][tx * 4];
        float av[4] = {a.x, a.y, a.z, a.w};
        float bv[4] = {b.x, b.y, b.z, b.w};
#pragma unroll
        for (int i = 0; i < 4; ++i)
#pragma unroll
          for (int j2 = 0; j2 < 4; ++j2)
            acc[i][j2] = fmaf(av[i], bv[j2], acc[i][j2]);
      }
      __syncthreads();
    }
#pragma unroll
    for (int i = 0; i < 4; ++i) {
      union { __bf16 h[4]; uint2 u; } ph, pl;
#pragma unroll
      for (int j = 0; j < 4; ++j) {
        __bf16 hb = (__bf16)acc[i][j];
        ph.h[j] = hb;
        pl.h[j] = (__bf16)(acc[i][j] - (float)hb);
      }
      size_t off = (size_t)(m0 + ty * 4 + i) * 256 + n0 + tx * 4;
      *(uint2*)(Wch + off) = ph.u;
      *(uint2*)(Wcl + off) = pl.u;
    }
  } else if (bx < 32) {
    // ---- bcomb = Wfc @ bo + bfc ----
    float* red = sh;
    int r = tid >> 4, c = tid & 15;
    int row = (bx - 16) * 16 + r;
    float s = 0.0f;
    for (int k = c; k < 256; k += 16) s = fmaf(Wfc[(size_t)row * 256 + k], bo[k], s);
    red[tid] = s;
    __syncthreads();
    if (c == 0) {
      float t = 0.0f;
#pragma unroll
      for (int i = 0; i < 16; ++i) t += red[r * 16 + i];
      bcomb[row] = t + bfc[row];
    }
  } else {
    // ---- split fp32 -> bf16 h + residual l ----
    int g = (bx - 32) * 256 + tid;
    const float* src;
    __bf16 *dh, *dl;
    if (g < 131072) {                     // x: 1,048,576 floats
      src = x + (size_t)g * 8; dh = xh + (size_t)g * 8; dl = xl + (size_t)g * 8;
    } else {
      int e = g - 131072;                 // 0..24575
      int wsel = e >> 13;
      int inner = (e & 8191) * 8;
      src = (wsel == 0 ? Wq : (wsel == 1 ? Wk : Wv)) + inner;
      dh = Ws + wsel * 131072 + inner;
      dl = Ws + wsel * 131072 + 65536 + inner;
    }
    union { __bf16 h[8]; uint4 u; } ph, pl;
#pragma unroll
    for (int i = 0; i < 2; ++i) {
      float4 v = *(const float4*)(src + i * 4);
      float vv[4] = {v.x, v.y, v.z, v.w};
#pragma unroll
      for (int j = 0; j < 4; ++j) {
        __bf16 hb = (__bf16)vv[j];
        ph.h[i * 4 + j] = hb;
        pl.h[i * 4 + j] = (__bf16)(vv[j] - (float)hb);
      }
    }
    *(uint4*)dh = ph.u;
    *(uint4*)dl = pl.u;
  }
}

// ---------------------------------------------------------------------------
// Fused QKV projection, split-bf16 MFMA. Grid (64, 12), 4 waves.
__global__ __launch_bounds__(256)
void gemm_qkv_mfma(const __bf16* __restrict__ xh, const __bf16* __restrict__ xl,
                   const __bf16* __restrict__ Ws,
                   const float* __restrict__ bq, const float* __restrict__ bk,
                   const float* __restrict__ bv,
                   float* __restrict__ Qb, float* __restrict__ Kb,
                   float* __restrict__ Vb) {
  const int tid = threadIdx.x, w = tid >> 6, lane = tid & 63;
  const int l15 = lane & 15, lg = lane >> 4;
  const int m0 = blockIdx.x * 64, nb = blockIdx.y;
  const int wsel = nb >> 2;
  const int n256b = (nb & 3) * 64;
  const __bf16* Wh = Ws + wsel * 131072;
  const __bf16* Wl = Wh + 65536;
  const int arow = m0 + w * 16 + l15;
  const __bf16* axh = xh + (size_t)arow * 256 + lg * 8;
  const __bf16* axl = xl + (size_t)arow * 256 + lg * 8;
  f32x4 acc0 = {0,0,0,0}, acc1 = {0,0,0,0}, acc2 = {0,0,0,0}, acc3 = {0,0,0,0};
#pragma unroll
  for (int k0 = 0; k0 < 256; k0 += 32) {
    bf16x8 ah = *(const bf16x8*)(axh + k0);
    bf16x8 al = *(const bf16x8*)(axl + k0);
#pragma unroll
    for (int g = 0; g < 4; ++g) {
      const size_t br = (size_t)(n256b + g * 16 + l15) * 256 + lg * 8 + k0;
      bf16x8 bh = *(const bf16x8*)(Wh + br);
      bf16x8 bl = *(const bf16x8*)(Wl + br);
      f32x4& acc = g == 0 ? acc0 : (g == 1 ? acc1 : (g == 2 ? acc2 : acc3));
      acc = __builtin_amdgcn_mfma_f32_16x16x32_bf16(ah, bh, acc, 0, 0, 0);
      acc = __builtin_amdgcn_mfma_f32_16x16x32_bf16(al, bh, acc, 0, 0, 0);
      acc = __builtin_amdgcn_mfma_f32_16x16x32_bf16(ah, bl, acc, 0, 0, 0);
    }
  }
  const float* bias = wsel == 0 ? bq : (wsel == 1 ? bk : bv);
  float* C = wsel == 0 ? Qb : (wsel == 1 ? Kb : Vb);
#pragma unroll
  for (int g = 0; g < 4; ++g) {
    const f32x4& acc = g == 0 ? acc0 : (g == 1 ? acc1 : (g == 2 ? acc2 : acc3));
    int n256 = n256b + g * 16 + l15;
    float bval = bias[n256];
    int h = n256 >> 5, d = n256 & 31;
#pragma unroll
    for (int r = 0; r < 4; ++r) {
      int m = m0 + w * 16 + lg * 4 + r;
      int b = m >> 11, s = m & 2047;
      C[((size_t)((b << 3) + h) << 16) + (size_t)s * 32 + d] = acc[r] + bval;
    }
  }
}

// ---------------------------------------------------------------------------
// K3: fused {prep_qk (blocks 0-255, K-blocks also reduce kkmin/Bkmax)}
//     {prep_vt (256-767)} {vsum from fp32 V (768-895)}.
__global__ __launch_bounds__(256)
void k3_prep(const float* __restrict__ Qf, const float* __restrict__ Kf,
             const float* __restrict__ Vf,
             __bf16* __restrict__ Qbf, __bf16* __restrict__ Kbf,
             __bf16* __restrict__ Vt,
             float4* __restrict__ qtab4, float4* __restrict__ ktab4,
             float* __restrict__ Vsum, float2* __restrict__ Kred) {
  __shared__ float2 red2[256];
  const int bx = blockIdx.x, tid = threadIdx.x;
  if (bx < 256) {
    // ---- expmap0 -> bf16 rows + tables ----
    int idx = bx * 256 + tid;                 // 0..65535
    const bool isQ = idx < 32768;
    const int i2 = isQ ? idx : idx - 32768;
    const float* src = (isQ ? Qf : Kf) + (size_t)i2 * 32;
    __bf16* dst = (isQ ? Qbf : Kbf) + (size_t)i2 * 32;
    float v[32];
    float ss = 0.0f;
#pragma unroll
    for (int i = 0; i < 8; ++i) {
      float4 v4 = *(const float4*)&src[i * 4];
      v[i*4+0] = v4.x; v[i*4+1] = v4.y; v[i*4+2] = v4.z; v[i*4+3] = v4.w;
      ss = fmaf(v4.x, v4.x, ss); ss = fmaf(v4.y, v4.y, ss);
      ss = fmaf(v4.z, v4.z, ss); ss = fmaf(v4.w, v4.w, ss);
    }
    ss = fmaxf(ss, 1e-12f);
    float x  = sqrtf(ss);
    float ex = fast_exp2(-2.8853900817779268f * x);     // e^{-2x}
    float opex = 1.0f + ex;
    float th = (1.0f - ex) / opex;
    float sc = th / x;
    float qq = th * th;
    float Bv = 4.0f * ex / (opex * opex);                // 1 - qq, exact
    float lgB = 2.0f - 2.8853900817779268f * x - 2.0f * fast_log2(opex);
    if (isQ) qtab4[i2] = float4{qq, ALPHA * lgB, Bv, 0.0f};
    else     ktab4[i2] = float4{qq, Bv, ALPHA * lgB, 0.0f};
    union { __bf16 h[8]; uint4 u; } pk;
#pragma unroll
    for (int blk = 0; blk < 4; ++blk) {
#pragma unroll
      for (int j = 0; j < 8; ++j) pk.h[j] = (__bf16)(v[blk * 8 + j] * sc);
      *(uint4*)(dst + blk * 8) = pk.u;
    }
    if (!isQ) {   // block-uniform: blocks 128..255 are all-K
      red2[tid] = float2{qq, Bv};
      __syncthreads();
      for (int s = 128; s > 0; s >>= 1) {
        if (tid < s) {
          red2[tid].x = fminf(red2[tid].x, red2[tid + s].x);
          red2[tid].y = fmaxf(red2[tid].y, red2[tid + s].y);
        }
        __syncthreads();
      }
      if (tid == 0) Kred[bx - 128] = red2[0];  // 8 partials per bh
    }
  } else if (bx < 768) {
    // ---- V[bh][t][dh] fp32 -> V^T[bh][dh][t] bf16 ----
    int g = (bx - 256) * 256 + tid;           // 0..131071
    int bh = g >> 13, rem = g & 8191;
    int tb = rem >> 5, dh = rem & 31;
    const float* src = Vf + (((size_t)bh * 2048 + tb * 8) * 32) + dh;
    union { __bf16 h[8]; uint4 u; } pk;
#pragma unroll
    for (int e = 0; e < 8; ++e) pk.h[e] = (__bf16)src[e * 32];
    *(uint4*)(Vt + ((size_t)bh * 32 + dh) * 2048 + tb * 8) = pk.u;
  } else {
    // ---- Vsum32[bh][t32][dh] = sum_{j<32} V[bh][t32*32+j][dh] (fp32) ----
    int g = (bx - 768) * 256 + tid;           // 0..32767
    int bh = g >> 11, rem = g & 2047;
    int t32 = rem >> 5, dh = rem & 31;
    const float* src = Vf + (((size_t)bh * 2048 + t32 * 32) * 32) + dh;
    float s = 0.0f;
#pragma unroll
    for (int j = 0; j < 32; ++j) s += src[j * 32];
    Vsum[((size_t)bh * 64 + t32) * 32 + dh] = s;
  }
}

// ---------------------------------------------------------------------------
// Flash attention, scalar-conservative clip test + double-buffered K staging.
// Vsum loads hoisted to tile-start (latency hidden under MFMA/test).
// Grid (32, 4, 16), 4 waves.
__global__ __launch_bounds__(256)
void attn_mfma(const __bf16* __restrict__ Qbf, const __bf16* __restrict__ Kbf,
               const __bf16* __restrict__ Vt,  const float4* __restrict__ qtab4,
               const float4* __restrict__ ktab4, const float* __restrict__ Vsum,
               const float2* __restrict__ Kred,
               float* __restrict__ PN, float* __restrict__ PD) {
  __shared__ __bf16 Kst[2][2048];    // 2 x (64 t x 32 dh), chunk-swizzled
  __shared__ __bf16 Pt[4][16][72];   // rare-path per-wave P^T
  const int tid = threadIdx.x;
  const int wid = tid >> 6, lane = tid & 63;
  const int l15 = lane & 15, lg = lane >> 4;
  const int tc = blockIdx.y, bh = blockIdx.z;
  const int sblk = blockIdx.x;
  const int s0 = sblk * 64 + wid * 16;

  bf16x8 qfrag = *(const bf16x8*)(Qbf + ((size_t)bh * 2048 + s0 + l15) * 32 + lg * 8);
  float4 qt = qtab4[bh * 2048 + s0 + l15];
  const float qq = qt.x, Bq = qt.z;
  const float eminRow = EMIN - qt.y;
  const float wclipf = (float)(__bf16)fast_exp2(eminRow);   // bf16-quantized
  float wrow[4];
#pragma unroll
  for (int r = 0; r < 4; ++r)
    wrow[r] = (float)(__bf16)fast_exp2(EMIN - qtab4[bh * 2048 + s0 + lg * 4 + r].y);

  // conservative per-row clip threshold: max(S) <= thr_all => whole subtile clips
  float kkmin = 1.0f, bkmax = 0.0f;
#pragma unroll
  for (int j = 0; j < 8; ++j) {
    float2 kr = Kred[bh * 8 + j];
    kkmin = fminf(kkmin, kr.x);
    bkmax = fmaxf(bkmax, kr.y);
  }
  const float thr_all = fmaf(0.5f * qq, kkmin,
                             fmaf(Bq * NEG_INV_2CHI, bkmax, 0.5f));

  const __bf16* Kbase = Kbf + ((size_t)bh << 16);
  const __bf16* Vbase = Vt + ((size_t)bh << 16);
  const float4* Tk = ktab4 + bh * 2048;
  const float*  VsBase = Vsum + (size_t)bh * 64 * 32;
  __bf16* Pw = &Pt[wid][0][0];

  f32x4 accO0 = {0.f, 0.f, 0.f, 0.f};
  f32x4 accO1 = {0.f, 0.f, 0.f, 0.f};
  float den = 0.0f;
  int nclip = 0;
  const f32x4 zero = {0.f, 0.f, 0.f, 0.f};
  const int tbeg = tc * 512;
  const int stag = sblk & 7;

  const int slot = wid * 64 + lane;          // 16B chunk index 0..255
  const int gch = slot ^ ((slot >> 2) & 3);  // involutive chunk XOR within row

  {  // prologue: stage tile 0 into buffer 0
    const int t0 = tbeg + ((stag & 7) << 6);
    load_lds16(Kbase + (size_t)t0 * 32 + gch * 8, &Kst[0][wid * 512]);
  }
  int cur = 0;

  for (int i = 0; i < 8; ++i) {
    __syncthreads();   // stage of buf[cur] drained; reads of buf[cur^1] done
    if (i < 7) {
      const int tn = tbeg + (((i + 1 + stag) & 7) << 6);
      load_lds16(Kbase + (size_t)tn * 32 + gch * 8, &Kst[cur ^ 1][wid * 512]);
    }
    const int t0 = tbeg + (((i + stag) & 7) << 6);
    const __bf16* Kc = &Kst[cur][0];

    // Hoisted Vsum loads for both halves: addresses depend only on t0, so
    // issue them NOW — their ~200cy L2 latency hides under MFMA + clip test
    // instead of sitting branch-dependent inside the fast path.
    const int ti32 = t0 >> 5;
    const float vsA[2] = { VsBase[ti32 * 32 + l15],        VsBase[(ti32 + 1) * 32 + l15] };
    const float vsB[2] = { VsBase[ti32 * 32 + 16 + l15],   VsBase[(ti32 + 1) * 32 + 16 + l15] };

    __builtin_amdgcn_s_setprio(1);
#pragma unroll
    for (int h = 0; h < 2; ++h) {
      f32x4 S[2];
      bool ok = true;
#pragma unroll
      for (int s2 = 0; s2 < 2; ++s2) {
        const int sub = h * 2 + s2;
        const int R = sub * 16 + l15;
        const int slotR = R * 4 + (lg ^ (R & 3));
        bf16x8 kfrag = *(const bf16x8*)&Kc[slotR * 8];
        f32x4 Sv = __builtin_amdgcn_mfma_f32_16x16x32_bf16(kfrag, qfrag, zero, 0, 0, 0);
        S[s2] = Sv;
        float m = fmaxf(fmaxf(Sv[0], Sv[1]), fmaxf(Sv[2], Sv[3]));
        ok &= (m <= thr_all);
      }
      if (__all((int)ok)) {
        // whole 32-t half clipped: rank-1 update, no PV.
        // 4 lanes (lg) share this q-row; lg-reduction sums them -> 8*wclip each.
        ++nclip;
#pragma unroll
        for (int r = 0; r < 4; ++r) {
          accO0[r] = fmaf(wrow[r], vsA[h], accO0[r]);
          accO1[r] = fmaf(wrow[r], vsB[h], accO1[r]);
        }
      } else {
        // rare: exact chain for both subtiles (ktab4 from L2), PV MFMA
#pragma unroll
        for (int s2 = 0; s2 < 2; ++s2) {
          const int sub = h * 2 + s2;
          const int tk = t0 + sub * 16 + lg * 4;
          f32x4 Sv = S[s2];
          float w[4];
#pragma unroll
          for (int r = 0; r < 4; ++r) {
            float4 T = Tk[tk + r];                   // kk, Bk, aLgBk
            float qk2 = Sv[r] + Sv[r];
            float u = (qq + T.x) - qk2;
            float d = fmaf(qq, T.x, 1.0f) - qk2;
            float p = fmaxf(u * d, 0.0f);
            float sq = sqrtf(p);
            float m = fmaf(2.0f, sq, u + d);
            float e = fmaf(-ALPHA, fast_log2(m), T.z);
            e = fmaxf(e, eminRow);
            w[r] = fast_exp2(e);
          }
          den += (w[0] + w[1]) + (w[2] + w[3]);
          union { __bf16 hh[4]; uint2 u2; } pk;
          pk.hh[0] = (__bf16)w[0]; pk.hh[1] = (__bf16)w[1];
          pk.hh[2] = (__bf16)w[2]; pk.hh[3] = (__bf16)w[3];
          *(uint2*)&Pw[l15 * 72 + sub * 16 + lg * 4] = pk.u2;
        }
        bf16x8 pfrag = *(const bf16x8*)&Pw[l15 * 72 + h * 32 + lg * 8];
        bf16x8 v0 = *(const bf16x8*)(Vbase + (size_t)l15 * 2048 + t0 + h * 32 + lg * 8);
        bf16x8 v1 = *(const bf16x8*)(Vbase + (size_t)(16 + l15) * 2048 + t0 + h * 32 + lg * 8);
        accO0 = __builtin_amdgcn_mfma_f32_16x16x32_bf16(pfrag, v0, accO0, 0, 0, 0);
        accO1 = __builtin_amdgcn_mfma_f32_16x16x32_bf16(pfrag, v1, accO1, 0, 0, 0);
      }
    }
    __builtin_amdgcn_s_setprio(0);
    cur ^= 1;
  }
  den = fmaf(8.0f * wclipf, (float)nclip, den);
  den += __shfl_xor(den, 16);
  den += __shfl_xor(den, 32);
  size_t pbase = ((size_t)tc * 16 + bh) * 2048;
  if (lg == 0) PD[pbase + s0 + l15] = den;
#pragma unroll
  for (int r = 0; r < 4; ++r) {
    int sl = lg * 4 + r;
    size_t row = (pbase + s0 + sl) * 32;
    PN[row + l15]      = accO0[r];
    PN[row + 16 + l15] = accO1[r];
  }
}

// ---------------------------------------------------------------------------
// Sum the 4 t-chunk partials, normalize, write AO as bf16 (h, l) pair.
__global__ __launch_bounds__(256)
void combine4(const float* __restrict__ PN, const float* __restrict__ PD,
              __bf16* __restrict__ AOh, __bf16* __restrict__ AOl) {
  int idx = blockIdx.x * 256 + threadIdx.x;   // 0..32767 = (bh, s)
  int bh = idx >> 11, s = idx & 2047;
  int b = bh >> 3, h = bh & 7;
  float den = 0.0f;
#pragma unroll
  for (int c = 0; c < 4; ++c) den += PD[((size_t)c * 16 + bh) * 2048 + s];
  float r = 1.0f / den;
  size_t ob = ((size_t)b * 2048 + s) * 256 + h * 32;
#pragma unroll
  for (int i = 0; i < 8; ++i) {
    float4 sum = {0.0f, 0.0f, 0.0f, 0.0f};
#pragma unroll
    for (int c = 0; c < 4; ++c) {
      float4 v = *(const float4*)&PN[((((size_t)c * 16 + bh) * 2048 + s) * 32) + i * 4];
      sum.x += v.x; sum.y += v.y; sum.z += v.z; sum.w += v.w;
    }
    float vv[4] = {sum.x * r, sum.y * r, sum.z * r, sum.w * r};
    union { __bf16 h4[4]; uint2 u; } ph, pl;
#pragma unroll
    for (int j = 0; j < 4; ++j) {
      __bf16 hb = (__bf16)vv[j];
      ph.h4[j] = hb;
      pl.h4[j] = (__bf16)(vv[j] - (float)hb);
    }
    *(uint2*)(AOh + ob + i * 4) = ph.u;
    *(uint2*)(AOl + ob + i * 4) = pl.u;
  }
}

// ---------------------------------------------------------------------------
// Output projection, split-bf16 MFMA: out = AO @ Wcomb^T + bcomb. Grid (64,4).
__global__ __launch_bounds__(256)
void gemm_out_mfma(const __bf16* __restrict__ aoh, const __bf16* __restrict__ aol,
                   const __bf16* __restrict__ Wch, const __bf16* __restrict__ Wcl,
                   const float* __restrict__ bcomb, float* __restrict__ out) {
  const int tid = threadIdx.x, w = tid >> 6, lane = tid & 63;
  const int l15 = lane & 15, lg = lane >> 4;
  const int m0 = blockIdx.x * 64, n0 = blockIdx.y * 64;
  const int arow = m0 + w * 16 + l15;
  const __bf16* axh = aoh + (size_t)arow * 256 + lg * 8;
  const __bf16* axl = aol + (size_t)arow * 256 + lg * 8;
  f32x4 acc0 = {0,0,0,0}, acc1 = {0,0,0,0}, acc2 = {0,0,0,0}, acc3 = {0,0,0,0};
#pragma unroll
  for (int k0 = 0; k0 < 256; k0 += 32) {
    bf16x8 ah = *(const bf16x8*)(axh + k0);
    bf16x8 al = *(const bf16x8*)(axl + k0);
#pragma unroll
    for (int g = 0; g < 4; ++g) {
      const size_t br = (size_t)(n0 + g * 16 + l15) * 256 + lg * 8 + k0;
      bf16x8 bh = *(const bf16x8*)(Wch + br);
      bf16x8 bl = *(const bf16x8*)(Wcl + br);
      f32x4& acc = g == 0 ? acc0 : (g == 1 ? acc1 : (g == 2 ? acc2 : acc3));
      acc = __builtin_amdgcn_mfma_f32_16x16x32_bf16(ah, bh, acc, 0, 0, 0);
      acc = __builtin_amdgcn_mfma_f32_16x16x32_bf16(al, bh, acc, 0, 0, 0);
      acc = __builtin_amdgcn_mfma_f32_16x16x32_bf16(ah, bl, acc, 0, 0, 0);
    }
  }
#pragma unroll
  for (int g = 0; g < 4; ++g) {
    const f32x4& acc = g == 0 ? acc0 : (g == 1 ? acc1 : (g == 2 ? acc2 : acc3));
    int n = n0 + g * 16 + l15;
    float bval = bcomb[n];
#pragma unroll
    for (int r = 0; r < 4; ++r) {
      int m = m0 + w * 16 + lg * 4 + r;
      out[(size_t)m * 256 + n] = acc[r] + bval;
    }
  }
}

// ---------------------------------------------------------------------------
extern "C" void kernel_launch(void* const* d_in, const int* in_sizes, int n_in,
                              void* d_out, int out_size, void* d_ws, size_t ws_size,
                              hipStream_t stream) {
  const float* x   = (const float*)d_in[0];
  const float* Wq  = (const float*)d_in[1];
  const float* bq  = (const float*)d_in[2];
  const float* Wk  = (const float*)d_in[3];
  const float* bk  = (const float*)d_in[4];
  const float* Wv  = (const float*)d_in[5];
  const float* bv  = (const float*)d_in[6];
  const float* Wo  = (const float*)d_in[7];
  const float* bo  = (const float*)d_in[8];
  const float* Wfc = (const float*)d_in[9];
  const float* bfc = (const float*)d_in[10];

  float* ws = (float*)d_ws;
  // Workspace layout (float offsets); ~41.7 MB total.
  float* Qb  = ws;                                      // 1M
  float* Kb  = ws + (1 << 20);                          // 1M
  float* Vb  = ws + (2 << 20);                          // 1M
  __bf16* Qbf = (__bf16*)(ws + (3 << 20));              // 1M bf16
  __bf16* Kbf = (__bf16*)(ws + (3 << 20) + (1 << 19));  // 1M bf16
  __bf16* Vtb = (__bf16*)(ws + (4 << 20));              // 1M bf16
  float4* qtab4 = (float4*)(ws + (4 << 20) + (1 << 19));             // 128K f
  float4* ktab4 = (float4*)(ws + (4 << 20) + (1 << 19) + (1 << 17)); // 128K f
  float*  Vsum  = ws + (4 << 20) + (1 << 19) + (2 << 17);            // 32K f
  __bf16* Wch   = (__bf16*)(Vsum + (1 << 15));          // 64K bf16 (32K f)
  __bf16* Wcl   = Wch + 65536;                          // 64K bf16
  float*  bcomb = Vsum + (1 << 15) + (1 << 16);         // 256
  float2* Kred  = (float2*)(bcomb + 256);               // 128 float2
  __bf16* xh = (__bf16*)(ws + (5 << 20));               // 1M bf16
  __bf16* xl = (__bf16*)(ws + (5 << 20) + (1 << 19));   // 1M bf16
  __bf16* Wsplit = (__bf16*)(ws + (6 << 20));           // 393216 bf16
  float* PN = ws + (6 << 20) + (1 << 18);               // 4M
  float* PD = PN + (4 << 20);                           // 128K
  __bf16* AOh = (__bf16*)ws;                            // reuse Qb slab
  __bf16* AOl = (__bf16*)(ws + (1 << 19));              // reuse Qb slab

  dim3 blk(256);
  k1_misc<<<dim3(640), blk, 0, stream>>>(x, Wq, Wk, Wv, Wfc, Wo, bo, bfc,
                                         xh, xl, Wsplit, Wch, Wcl, bcomb);
  gemm_qkv_mfma<<<dim3(64, 12), blk, 0, stream>>>(xh, xl, Wsplit, bq, bk, bv,
                                                  Qb, Kb, Vb);
  k3_prep<<<dim3(896), blk, 0, stream>>>(Qb, Kb, Vb, Qbf, Kbf, Vtb,
                                         qtab4, ktab4, Vsum, Kred);
  attn_mfma<<<dim3(32, 4, 16), blk, 0, stream>>>(Qbf, Kbf, Vtb, qtab4, ktab4,
                                                 Vsum, Kred, PN, PD);
  combine4<<<dim3(128), blk, 0, stream>>>(PN, PD, AOh, AOl);
  gemm_out_mfma<<<dim3(64, 4), blk, 0, stream>>>(AOh, AOl, Wch, Wcl, bcomb,
                                                 (float*)d_out);
}